// Round 1
// baseline (96.041 us; speedup 1.0000x reference)
//
#include <hip/hip_runtime.h>

#define L_SEQ 2048
#define HEADS 16
#define DIM   64
#define TILE  32
#define HALO  (TILE + 2)   // 34 content rows: l0-1 .. l0+32

// One block = (b, h, 32 consecutive l). 256 threads = 4 waves.
// Phase 1: content[g] = W @ x[b,g,h,:] + bias for g in [l0-1, l0+32]  (clamped)
//          lane e holds W[e,0:64] in 64 VGPRs; x row is wave-uniform (scalarized).
// Phase 2: 65 squared-norm reductions (33 x d1^2, 32 x d2^2) via shfl_xor.
// Phase 3: per (l, j) pair: score -> adjust -> adj_pos -> interpolated RoPE.
__global__ __launch_bounds__(256) void betweenness_rope_kernel(
    const float* __restrict__ x, const float* __restrict__ W,
    const float* __restrict__ bias, const float* __restrict__ gate,
    float* __restrict__ out)
{
    __shared__ float cs[HALO][DIM];   // content rows (local r -> global l0-1+r)
    __shared__ float n1s[HALO - 1];   // ||c[r+1]-c[r]||^2, r=0..32
    __shared__ float n2s[HALO - 2];   // ||c[r+2]-c[r]||^2, r=0..31

    const int tid  = threadIdx.x;
    const int lane = tid & 63;
    const int wave = tid >> 6;
    const int l0   = blockIdx.x * TILE;
    const int h    = blockIdx.y;
    const int b    = blockIdx.z;

    // ---- W row into registers (lane e = output channel e) ----
    float wreg[DIM];
    {
        const float4* Wr = (const float4*)(W + lane * DIM);
        #pragma unroll
        for (int k4 = 0; k4 < DIM / 4; ++k4) {
            float4 wv = Wr[k4];
            wreg[4 * k4 + 0] = wv.x; wreg[4 * k4 + 1] = wv.y;
            wreg[4 * k4 + 2] = wv.z; wreg[4 * k4 + 3] = wv.w;
        }
    }
    const float bval = bias[lane];

    // offset of (b, l=0, h, 0) in elements
    const int bh_off = (b * L_SEQ * HEADS + h) * DIM;

    // ---- Phase 1: content rows ----
    for (int r = wave; r < HALO; r += 4) {
        int g = l0 - 1 + r;
        g = max(0, min(L_SEQ - 1, g));            // clamped halo only feeds masked outputs
        int off = bh_off + g * (HEADS * DIM);
        off = __builtin_amdgcn_readfirstlane(off); // wave-uniform -> scalar loads
        const float4* xr = (const float4*)(x + off);
        float acc = bval;
        #pragma unroll
        for (int k4 = 0; k4 < DIM / 4; ++k4) {
            float4 xv = xr[k4];
            acc = fmaf(xv.x, wreg[4 * k4 + 0], acc);
            acc = fmaf(xv.y, wreg[4 * k4 + 1], acc);
            acc = fmaf(xv.z, wreg[4 * k4 + 2], acc);
            acc = fmaf(xv.w, wreg[4 * k4 + 3], acc);
        }
        cs[r][lane] = acc;
    }
    __syncthreads();

    // ---- Phase 2: squared norms ----
    for (int idx = wave; idx < 65; idx += 4) {
        int i  = (idx < 33) ? idx : idx - 33;
        int da = (idx < 33) ? 1 : 2;
        float d = cs[i + da][lane] - cs[i][lane];
        float p = d * d;
        #pragma unroll
        for (int m = 1; m < 64; m <<= 1) p += __shfl_xor(p, m, 64);
        if (lane == 0) {
            if (idx < 33) n1s[i] = p; else n2s[i] = p;
        }
    }
    __syncthreads();

    // ---- Phase 3: RoPE epilogue ----
    const float gate0 = gate[0];
    const int j    = lane & 31;    // pair index (d = 2j, 2j+1)
    const int half = lane >> 5;
    // f_j = 10000^(-j/32) = 2^(-j * log2(10000)/32)
    const float fj = exp2f((float)j * -0.4152410118609203f);
    float sf, cf;
    sincosf(fj, &sf, &cf);         // rotation by one position step

    #pragma unroll
    for (int it = 0; it < 4; ++it) {
        int r = it * 8 + wave * 2 + half;   // 0..31 output row within tile
        int l = l0 + r;

        float d1a = sqrtf(n1s[r]);
        float d1b = sqrtf(n1s[r + 1]);
        float dd  = sqrtf(n2s[r]);
        float sc  = fmaxf(1.0f - ((d1a + d1b) - dd) / fmaxf(dd, 1e-6f), 0.0f);
        float bet = (l >= 1 && l <= L_SEQ - 2) ? sc * (1.0f / (L_SEQ - 2)) : 0.0f;
        float adjust = gate0 * (bet - 0.5f) * 0.1f;
        float ap  = fminf(fmaxf((float)l + adjust, 0.0f), (float)(L_SEQ - 1));
        float flo = floorf(ap);
        float frac = ap - flo;

        float ang = flo * fj;
        float s_lo, c_lo;
        sincosf(ang, &s_lo, &c_lo);
        float c_hi = c_lo * cf - s_lo * sf;   // cos((lo+1)*fj)
        float s_hi = s_lo * cf + c_lo * sf;   // sin((lo+1)*fj)
        float ci = c_lo + frac * (c_hi - c_lo);
        float si = s_lo + frac * (s_hi - s_lo);

        int off = bh_off + l * (HEADS * DIM);
        const float2* xp = (const float2*)(x + off);
        float2 xv = xp[j];
        float2 o;
        o.x = xv.x * ci - xv.y * si;
        o.y = xv.y * ci + xv.x * si;
        ((float2*)(out + off))[j] = o;
    }
}

extern "C" void kernel_launch(void* const* d_in, const int* in_sizes, int n_in,
                              void* d_out, int out_size, void* d_ws, size_t ws_size,
                              hipStream_t stream) {
    const float* x    = (const float*)d_in[0];
    const float* W    = (const float*)d_in[1];
    const float* bias = (const float*)d_in[2];
    const float* gate = (const float*)d_in[3];
    float* out = (float*)d_out;

    const int B = in_sizes[0] / (L_SEQ * HEADS * DIM);
    dim3 grid(L_SEQ / TILE, HEADS, B);
    betweenness_rope_kernel<<<grid, 256, 0, stream>>>(x, W, bias, gate, out);
}

// Round 2
// 51.221 us; speedup vs baseline: 1.8750x; 1.8750x over previous
//
#include <hip/hip_runtime.h>

#define L_SEQ 2048
#define HEADS 16
#define DIM   64
#define TILE  32
#define XROWS 34          // x rows staged: l0-1 .. l0+32
#define XPITCH 68         // f32 pitch (272B, 16B-aligned, breaks some bank aliasing)
#define DROWS 48          // delta rows padded to 3 M-tiles of 16

typedef __attribute__((ext_vector_type(8))) short bf16x8;
typedef __attribute__((ext_vector_type(4))) float f32x4;
typedef __attribute__((ext_vector_type(8))) unsigned short u16x8;
typedef __attribute__((ext_vector_type(4))) unsigned short u16x4;

static __device__ __forceinline__ unsigned short f2bf(float f) {
    unsigned int u = __builtin_bit_cast(unsigned int, f);
    u += 0x7fffu + ((u >> 16) & 1u);        // RTNE (finite values only here)
    return (unsigned short)(u >> 16);
}

// bf16 LDS tiles have 64-ushort (128B) rows -> 16-way conflict unswizzled.
// XOR-swizzle (G4): ushort_col ^ ((row&7)<<3)  == byte ^ ((row&7)<<4).
#define SWZ(row, col) ((row) * 64 + ((col) ^ (((row) & 7) * 8)))

__global__ void prep_w_kernel(const float* __restrict__ W, unsigned short* __restrict__ wbf) {
    int i = blockIdx.x * 256 + threadIdx.x;
    if (i < DIM * DIM) wbf[i] = f2bf(W[i]);
}

// One block = (b, h, 32 consecutive l). 256 threads = 4 waves.
__global__ __launch_bounds__(256) void betweenness_rope_kernel(
    const float* __restrict__ x, const float* __restrict__ W,
    const unsigned short* __restrict__ wbf, const float* __restrict__ gate,
    float* __restrict__ out)
{
    __shared__ float xs[XROWS * XPITCH];          // staged x rows (f32)
    __shared__ unsigned short dlt[DROWS * 64];    // bf16 diff rows, swizzled
    __shared__ unsigned short wl[64 * 64];        // bf16 W rows, swizzled
    __shared__ unsigned short el[DROWS * 64];     // bf16 E rows, swizzled
    __shared__ float n1s[34];                     // G[r,r]   = ||E_r||^2
    __shared__ float g1s[33];                     // G[r,r+1] = E_r . E_{r+1}

    const int tid  = threadIdx.x;
    const int lane = tid & 63;
    const int wave = tid >> 6;
    const int l0   = blockIdx.x * TILE;
    const int h    = blockIdx.y;
    const int b    = blockIdx.z;
    const int bh_off = (b * L_SEQ * HEADS + h) * DIM;

    // ---- stage x rows (read x from HBM exactly once) ----
    for (int c = tid; c < XROWS * 16; c += 256) {
        int r = c >> 4, q = c & 15;
        int g = l0 - 1 + r; g = max(0, min(L_SEQ - 1, g));
        float4 v = *(const float4*)(x + bh_off + g * (HEADS * DIM) + q * 4);
        *(float4*)&xs[r * XPITCH + q * 4] = v;
    }
    // ---- stage W as bf16 (from prep kernel if workspace available) ----
    if (wbf) {
        for (int c = tid; c < 512; c += 256) {
            int r = c >> 3, q = (c & 7) * 8;
            u16x8 v = *(const u16x8*)(wbf + r * 64 + q);
            *(u16x8*)&wl[SWZ(r, q)] = v;
        }
    } else {
        for (int c = tid; c < 1024; c += 256) {
            int r = c >> 4, q = (c & 15) * 4;
            float4 v = *(const float4*)(W + r * 64 + q);
            u16x4 o = { f2bf(v.x), f2bf(v.y), f2bf(v.z), f2bf(v.w) };
            *(u16x4*)&wl[SWZ(r, q)] = o;
        }
    }
    __syncthreads();

    // ---- delta rows: dlt[r] = bf16(x[l0+r] - x[l0-1+r]), r=0..32; 33..47 zero ----
    for (int r = tid >> 3; r < DROWS; r += 32) {
        int c0 = (tid & 7) * 8;
        u16x8 o = {0, 0, 0, 0, 0, 0, 0, 0};
        if (r <= 32) {
            float4 a0 = *(float4*)&xs[r * XPITCH + c0];
            float4 a1 = *(float4*)&xs[r * XPITCH + c0 + 4];
            float4 b0 = *(float4*)&xs[(r + 1) * XPITCH + c0];
            float4 b1 = *(float4*)&xs[(r + 1) * XPITCH + c0 + 4];
            o[0] = f2bf(b0.x - a0.x); o[1] = f2bf(b0.y - a0.y);
            o[2] = f2bf(b0.z - a0.z); o[3] = f2bf(b0.w - a0.w);
            o[4] = f2bf(b1.x - a1.x); o[5] = f2bf(b1.y - a1.y);
            o[6] = f2bf(b1.z - a1.z); o[7] = f2bf(b1.w - a1.w);
        }
        *(u16x8*)&dlt[SWZ(r, c0)] = o;
    }
    __syncthreads();

    // ---- E = Delta @ W^T via MFMA. wave = N-tile (16 cols), loop 3 M-tiles ----
    {
        const int la = lane & 15, lg = lane >> 4;
        #pragma unroll
        for (int mt = 0; mt < 3; ++mt) {
            f32x4 acc = {0.f, 0.f, 0.f, 0.f};
            #pragma unroll
            for (int kt = 0; kt < 2; ++kt) {
                int cb = lg * 8 + kt * 32;
                int arow = 16 * mt + la;
                bf16x8 a = *(const bf16x8*)&dlt[SWZ(arow, cb)];
                int brow = 16 * wave + la;              // B[k][n] = W[n][k] -> row-major W read
                bf16x8 bb = *(const bf16x8*)&wl[SWZ(brow, cb)];
                acc = __builtin_amdgcn_mfma_f32_16x16x32_bf16(a, bb, acc, 0, 0, 0);
            }
            #pragma unroll
            for (int q = 0; q < 4; ++q) {               // D: col=lane&15, row=(lane>>4)*4+q
                int R = 16 * mt + lg * 4 + q, C = 16 * wave + la;
                el[SWZ(R, C)] = f2bf(acc[q]);
            }
        }
    }
    __syncthreads();

    // ---- Gram band via MFMA: tiles (0,0),(1,1),(2,2),(0,1),(1,2) ----
    {
        const int la = lane & 15, lg = lane >> 4;
        const int ntile = (wave == 0) ? 2 : 1;
        for (int s = 0; s < ntile; ++s) {
            int t = (s == 0) ? wave : 4;                // tile 3 = (0,1), tile 4 = (1,2)
            int mt = (t < 3) ? t : ((t == 3) ? 0 : 1);
            int nt = (t < 3) ? t : ((t == 3) ? 1 : 2);
            f32x4 g = {0.f, 0.f, 0.f, 0.f};
            #pragma unroll
            for (int kt = 0; kt < 2; ++kt) {
                int cb = lg * 8 + kt * 32;
                bf16x8 a  = *(const bf16x8*)&el[SWZ(16 * mt + la, cb)];
                bf16x8 bb = *(const bf16x8*)&el[SWZ(16 * nt + la, cb)];  // B[k][n]=E[n][k]
                g = __builtin_amdgcn_mfma_f32_16x16x32_bf16(a, bb, g, 0, 0, 0);
            }
            #pragma unroll
            for (int q = 0; q < 4; ++q) {
                int R = 16 * mt + lg * 4 + q, C = 16 * nt + la;
                if (C == R && R < 34) n1s[R] = g[q];
                if (C == R + 1 && R < 33) g1s[R] = g[q];
            }
        }
    }
    __syncthreads();

    // ---- RoPE epilogue: hw trig, x from LDS, coalesced float2 store ----
    {
        const int j = lane & 31, half = lane >> 5;
        const float gate0 = gate[0];
        // f_j = 10000^(-j/32); fjr = f_j / (2*pi)  (revolutions per position)
        const float fj  = __builtin_exp2f(-0.4152410118609203f * (float)j);
        const float fjr = fj * 0.15915494309189535f;
        #pragma unroll
        for (int it = 0; it < 4; ++it) {
            int r = it * 8 + wave * 2 + half;   // 0..31
            int l = l0 + r;

            float a1 = n1s[r], b1 = n1s[r + 1], gg = g1s[r];
            float d1a = sqrtf(a1), d1b = sqrtf(b1);
            float dd  = sqrtf(fmaxf(a1 + b1 + 2.f * gg, 0.f));   // ||E_r + E_{r+1}||
            float sc  = fmaxf(1.f - ((d1a + d1b) - dd) / fmaxf(dd, 1e-6f), 0.f);
            float bet = (l >= 1 && l <= L_SEQ - 2) ? sc * (1.f / (L_SEQ - 2)) : 0.f;
            float adjust = gate0 * (bet - 0.5f) * 0.1f;
            float ap  = fminf(fmaxf((float)l + adjust, 0.f), (float)(L_SEQ - 1));
            float flo = floorf(ap);
            float frac = ap - flo;

            float t0 = flo * fjr;               // revolutions at lo
            float t1 = t0 + fjr;                // revolutions at lo+1
            float r0 = t0 - floorf(t0);
            float r1 = t1 - floorf(t1);
            float c_lo = __builtin_amdgcn_cosf(r0), s_lo = __builtin_amdgcn_sinf(r0);
            float c_hi = __builtin_amdgcn_cosf(r1), s_hi = __builtin_amdgcn_sinf(r1);
            float ci = c_lo + frac * (c_hi - c_lo);
            float si = s_lo + frac * (s_hi - s_lo);

            float2 xv = *(const float2*)&xs[(r + 1) * XPITCH + 2 * j];
            float2 o;
            o.x = xv.x * ci - xv.y * si;
            o.y = xv.y * ci + xv.x * si;
            *(float2*)(out + bh_off + l * (HEADS * DIM) + 2 * j) = o;
        }
    }
}

extern "C" void kernel_launch(void* const* d_in, const int* in_sizes, int n_in,
                              void* d_out, int out_size, void* d_ws, size_t ws_size,
                              hipStream_t stream) {
    const float* x    = (const float*)d_in[0];
    const float* W    = (const float*)d_in[1];
    const float* gate = (const float*)d_in[3];   // bias cancels in differences
    float* out = (float*)d_out;

    const int B = in_sizes[0] / (L_SEQ * HEADS * DIM);

    unsigned short* wbf = nullptr;
    if (ws_size >= (size_t)(DIM * DIM * sizeof(unsigned short))) {
        wbf = (unsigned short*)d_ws;
        prep_w_kernel<<<16, 256, 0, stream>>>(W, wbf);
    }

    dim3 grid(L_SEQ / TILE, HEADS, B);
    betweenness_rope_kernel<<<grid, 256, 0, stream>>>(x, W, wbf, gate, out);
}

// Round 3
// 40.122 us; speedup vs baseline: 2.3937x; 1.2766x over previous
//
#include <hip/hip_runtime.h>

#define L_SEQ 2048
#define HEADS 16
#define DIM   64
#define TILE  32
#define XROWS 34          // x rows staged: l0-1 .. l0+32
#define XPITCH 68         // f32 pitch (272B)
#define DROWS 48          // delta/E rows padded to 3 M-tiles of 16

typedef __attribute__((ext_vector_type(8))) short bf16x8;
typedef __attribute__((ext_vector_type(4))) float f32x4;
typedef __attribute__((ext_vector_type(8))) unsigned short u16x8;

static __device__ __forceinline__ unsigned short f2bf(float f) {
    unsigned int u = __builtin_bit_cast(unsigned int, f);
    u += 0x7fffu + ((u >> 16) & 1u);        // RTNE (finite values only here)
    return (unsigned short)(u >> 16);
}

// bf16 LDS tiles have 64-ushort (128B) rows -> 16-way conflict unswizzled.
// XOR-swizzle: ushort_col ^ ((row&7)<<3)  == byte ^ ((row&7)<<4).
#define SWZ(row, col) ((row) * 64 + ((col) ^ (((row) & 7) * 8)))

__global__ void prep_w_kernel(const float* __restrict__ W, unsigned short* __restrict__ wbf) {
    int i = blockIdx.x * 256 + threadIdx.x;
    if (i < DIM * DIM) wbf[i] = f2bf(W[i]);
}

// One block = (b, h, 32 consecutive l). 256 threads = 4 waves.
__global__ __launch_bounds__(256) void betweenness_rope_kernel(
    const float* __restrict__ x, const float* __restrict__ W,
    const unsigned short* __restrict__ wbf, const float* __restrict__ gate,
    float* __restrict__ out)
{
    __shared__ float xs[XROWS * XPITCH];          // staged x rows (f32)
    __shared__ unsigned short dl[DROWS * 64];     // bf16 diff rows, then E rows (aliased)
    __shared__ float n1s[34];                     // G[r,r]   = ||E_r||^2
    __shared__ float g1s[33];                     // G[r,r+1] = E_r . E_{r+1}
    __shared__ float2 fl[32];                     // per-row {floor(adj_pos), frac}

    const int tid  = threadIdx.x;
    const int lane = tid & 63;
    const int wave = tid >> 6;
    const int la   = lane & 15, lg = lane >> 4;
    const int l0   = blockIdx.x * TILE;
    const int h    = blockIdx.y;
    const int b    = blockIdx.z;
    const int bh_off = (b * L_SEQ * HEADS + h) * DIM;

    // ---- Phase 1: stage x rows (x read from HBM exactly once) ----
    for (int c = tid; c < XROWS * 16; c += 256) {
        int r = c >> 4, q = c & 15;
        int g = l0 - 1 + r; g = max(0, min(L_SEQ - 1, g));
        float4 v = *(const float4*)(x + bh_off + g * (HEADS * DIM) + q * 4);
        *(float4*)&xs[r * XPITCH + q * 4] = v;
    }
    __syncthreads();

    // ---- Phase 2: delta rows dl[r] = bf16(x[l0+r] - x[l0-1+r]), r=0..32; 33..47 zero ----
    for (int r = tid >> 3; r < DROWS; r += 32) {
        int c0 = (tid & 7) * 8;
        u16x8 o = {0, 0, 0, 0, 0, 0, 0, 0};
        if (r <= 32) {
            float4 a0 = *(float4*)&xs[r * XPITCH + c0];
            float4 a1 = *(float4*)&xs[r * XPITCH + c0 + 4];
            float4 b0 = *(float4*)&xs[(r + 1) * XPITCH + c0];
            float4 b1 = *(float4*)&xs[(r + 1) * XPITCH + c0 + 4];
            o[0] = f2bf(b0.x - a0.x); o[1] = f2bf(b0.y - a0.y);
            o[2] = f2bf(b0.z - a0.z); o[3] = f2bf(b0.w - a0.w);
            o[4] = f2bf(b1.x - a1.x); o[5] = f2bf(b1.y - a1.y);
            o[6] = f2bf(b1.z - a1.z); o[7] = f2bf(b1.w - a1.w);
        }
        *(u16x8*)&dl[SWZ(r, c0)] = o;
    }
    __syncthreads();

    // ---- Phase 3: E = Delta @ W^T via MFMA; then overwrite dl with bf16(E) ----
    {
        // B fragments (rows of W = cols of W^T) straight from global (L2-hot 8KB table)
        bf16x8 bfrag[2];
        const int n = 16 * wave + la;
        if (wbf) {
            bfrag[0] = *(const bf16x8*)(wbf + n * 64 + lg * 8);
            bfrag[1] = *(const bf16x8*)(wbf + n * 64 + lg * 8 + 32);
        } else {
            #pragma unroll
            for (int kt = 0; kt < 2; ++kt) {
                const float* wr = W + n * 64 + lg * 8 + kt * 32;
                float4 w0 = *(const float4*)(wr);
                float4 w1 = *(const float4*)(wr + 4);
                u16x8 t = { f2bf(w0.x), f2bf(w0.y), f2bf(w0.z), f2bf(w0.w),
                            f2bf(w1.x), f2bf(w1.y), f2bf(w1.z), f2bf(w1.w) };
                bfrag[kt] = __builtin_bit_cast(bf16x8, t);
            }
        }
        bf16x8 afrag[3][2];
        #pragma unroll
        for (int mt = 0; mt < 3; ++mt)
            #pragma unroll
            for (int kt = 0; kt < 2; ++kt)
                afrag[mt][kt] = *(const bf16x8*)&dl[SWZ(16 * mt + la, lg * 8 + kt * 32)];
        f32x4 acc[3];
        #pragma unroll
        for (int mt = 0; mt < 3; ++mt) {
            f32x4 a_ = {0.f, 0.f, 0.f, 0.f};
            a_ = __builtin_amdgcn_mfma_f32_16x16x32_bf16(afrag[mt][0], bfrag[0], a_, 0, 0, 0);
            a_ = __builtin_amdgcn_mfma_f32_16x16x32_bf16(afrag[mt][1], bfrag[1], a_, 0, 0, 0);
            acc[mt] = a_;
        }
        __syncthreads();   // all delta reads complete before overwriting dl with E
        #pragma unroll
        for (int mt = 0; mt < 3; ++mt)
            #pragma unroll
            for (int q = 0; q < 4; ++q)   // D layout: col=lane&15, row=(lane>>4)*4+q
                dl[SWZ(16 * mt + lg * 4 + q, 16 * wave + la)] = f2bf(acc[mt][q]);
    }
    __syncthreads();

    // ---- Phase 4: Gram band via MFMA: tiles (0,0),(1,1),(2,2) + (0,1),(1,2) ----
    {
        const int ntile = (wave == 0) ? 2 : 1;
        for (int s = 0; s < ntile; ++s) {
            int t = (s == 0) ? wave : 4;                // wave3 -> (0,1); wave0 2nd -> (1,2)
            int mt = (t < 3) ? t : ((t == 3) ? 0 : 1);
            int nt = (t < 3) ? t : ((t == 3) ? 1 : 2);
            f32x4 g = {0.f, 0.f, 0.f, 0.f};
            #pragma unroll
            for (int kt = 0; kt < 2; ++kt) {
                int cb = lg * 8 + kt * 32;
                bf16x8 a  = *(const bf16x8*)&dl[SWZ(16 * mt + la, cb)];
                bf16x8 bb = *(const bf16x8*)&dl[SWZ(16 * nt + la, cb)];  // B[k][n]=E[n][k]
                g = __builtin_amdgcn_mfma_f32_16x16x32_bf16(a, bb, g, 0, 0, 0);
            }
            #pragma unroll
            for (int q = 0; q < 4; ++q) {
                int R = 16 * mt + lg * 4 + q, C = 16 * nt + la;
                if (C == R && R < 34) n1s[R] = g[q];
                if (C == R + 1 && R < 33) g1s[R] = g[q];
            }
        }
    }
    __syncthreads();

    // ---- Phase 5: per-row score -> (flo, frac), computed once (32 threads) ----
    if (tid < 32) {
        const float gate0 = gate[0];
        int r = tid, l = l0 + r;
        float a1 = n1s[r], b1 = n1s[r + 1], gg = g1s[r];
        float d1a = sqrtf(a1), d1b = sqrtf(b1);
        float dd  = sqrtf(fmaxf(a1 + b1 + 2.f * gg, 0.f));   // ||E_r + E_{r+1}||
        float sc  = fmaxf(1.f - ((d1a + d1b) - dd) / fmaxf(dd, 1e-6f), 0.f);
        float bet = (l >= 1 && l <= L_SEQ - 2) ? sc * (1.f / (L_SEQ - 2)) : 0.f;
        float adjust = gate0 * (bet - 0.5f) * 0.1f;
        float ap  = fminf(fmaxf((float)l + adjust, 0.f), (float)(L_SEQ - 1));
        float flo = floorf(ap);
        fl[r] = make_float2(flo, ap - flo);
    }
    __syncthreads();

    // ---- Phase 6: RoPE epilogue: 1 sincos + rotation, x from LDS ----
    {
        const int j = lane & 31, half = lane >> 5;
        // fjr = f_j / (2*pi): revolutions per position; f_j = 10000^(-j/32)
        const float fjr = __builtin_exp2f(-0.4152410118609203f * (float)j)
                        * 0.15915494309189535f;
        const float cf = __builtin_amdgcn_cosf(fjr);   // cos(f_j)  (fjr < 1, no fract needed)
        const float sf = __builtin_amdgcn_sinf(fjr);   // sin(f_j)
        const float cfm1 = cf - 1.0f;
        const int r0w = wave * 2 + half;               // base row 0..7
        const float* xbase = &xs[(r0w + 1) * XPITCH + 2 * j];
        float* obase = out + bh_off + (l0 + r0w) * (HEADS * DIM) + 2 * j;
        #pragma unroll
        for (int it = 0; it < 4; ++it) {
            int r = it * 8 + r0w;
            float2 ff = fl[r];
            float t0 = ff.x * fjr;                     // revolutions at lo
            float rv = t0 - floorf(t0);
            float c_lo = __builtin_amdgcn_cosf(rv);
            float s_lo = __builtin_amdgcn_sinf(rv);
            float u = fmaf(ff.y, cfm1, 1.0f);          // (1-frac) + frac*cf
            float v = ff.y * sf;                       // frac*sf
            float ci = fmaf(-s_lo, v, c_lo * u);       // interp cos
            float si = fmaf(c_lo, v, s_lo * u);        // interp sin
            float2 xv = *(const float2*)(xbase + it * 8 * XPITCH);
            float2 o;
            o.x = xv.x * ci - xv.y * si;
            o.y = fmaf(xv.y, ci, xv.x * si);
            *(float2*)(obase + it * 8 * (HEADS * DIM)) = o;
        }
    }
}

extern "C" void kernel_launch(void* const* d_in, const int* in_sizes, int n_in,
                              void* d_out, int out_size, void* d_ws, size_t ws_size,
                              hipStream_t stream) {
    const float* x    = (const float*)d_in[0];
    const float* W    = (const float*)d_in[1];
    const float* gate = (const float*)d_in[3];   // bias cancels in differences
    float* out = (float*)d_out;

    const int B = in_sizes[0] / (L_SEQ * HEADS * DIM);

    unsigned short* wbf = nullptr;
    if (ws_size >= (size_t)(DIM * DIM * sizeof(unsigned short))) {
        wbf = (unsigned short*)d_ws;
        prep_w_kernel<<<16, 256, 0, stream>>>(W, wbf);
    }

    dim3 grid(L_SEQ / TILE, HEADS, B);
    betweenness_rope_kernel<<<grid, 256, 0, stream>>>(x, W, wbf, gate, out);
}